// Round 6
// baseline (587.676 us; speedup 1.0000x reference)
//
#include <hip/hip_runtime.h>

#define NN 100000
#define NE 1200000
#define NF 64
#define NH 256
#define NC 40
#define ORDER_C 8
#define SC 1024  // scan chunk (elements per block)

// ---- bf16 helpers (RTNE pack, cheap unpack) ----
__device__ __forceinline__ unsigned bf16r(float x) {
    unsigned u = __float_as_uint(x);
    return (u + 0x7FFFu + ((u >> 16) & 1u)) >> 16;
}
__device__ __forceinline__ unsigned packbf(float lo, float hi) {
    return bf16r(lo) | (bf16r(hi) << 16);
}
__device__ __forceinline__ float bflo(unsigned u) { return __uint_as_float(u << 16); }
__device__ __forceinline__ float bfhi(unsigned u) { return __uint_as_float(u & 0xFFFF0000u); }

// ---------------- CSR build ----------------

static __global__ __launch_bounds__(256) void k_count(const int* __restrict__ rows,
                                                      int* __restrict__ cnt, int E)
{
    int i = blockIdx.x * 256 + threadIdx.x;
    if (i < E) atomicAdd(&cnt[rows[i]], 1);
}

// scan phase 1: per-block sums of 1024-element chunks
static __global__ __launch_bounds__(256) void k_bsum(const int* __restrict__ cnt,
                                                     int* __restrict__ bsum, int n)
{
    __shared__ int red[256];
    int t = threadIdx.x;
    int idx = blockIdx.x * SC + t * 4;
    int s = 0;
    if (idx + 3 < n) {
        int4 q = *(const int4*)&cnt[idx];
        s = q.x + q.y + q.z + q.w;
    } else {
        for (int j = 0; j < 4; ++j) if (idx + j < n) s += cnt[idx + j];
    }
    red[t] = s;
    __syncthreads();
    for (int off = 128; off > 0; off >>= 1) {
        if (t < off) red[t] += red[t + off];
        __syncthreads();
    }
    if (t == 0) bsum[blockIdx.x] = red[0];
}

// scan phase 2: single block scans block sums (nb <= 128); also writes rp[n]=total
static __global__ __launch_bounds__(128) void k_scanb(const int* __restrict__ bsum,
                                                      int* __restrict__ boff,
                                                      int* __restrict__ rp, int nb, int n)
{
    __shared__ int red[128];
    int t = threadIdx.x;
    int v = (t < nb) ? bsum[t] : 0;
    red[t] = v;
    __syncthreads();
    for (int off = 1; off < 128; off <<= 1) {
        int x = (t >= off) ? red[t - off] : 0;
        __syncthreads();
        red[t] += x;
        __syncthreads();
    }
    if (t < nb) boff[t] = (t == 0) ? 0 : red[t - 1];
    if (t == 0) rp[n] = red[127];
}

// scan phase 3: per-block local exclusive scan + block offset -> rp; also dinv
static __global__ __launch_bounds__(256) void k_scan3(const int* __restrict__ cnt,
                                                      const int* __restrict__ boff,
                                                      int* __restrict__ rp,
                                                      float* __restrict__ dinv, int n)
{
    __shared__ int red[256];
    int t = threadIdx.x;
    int idx = blockIdx.x * SC + t * 4;
    int v[4] = {0, 0, 0, 0};
    if (idx + 3 < n) {
        int4 q = *(const int4*)&cnt[idx];
        v[0] = q.x; v[1] = q.y; v[2] = q.z; v[3] = q.w;
    } else {
        for (int j = 0; j < 4; ++j) if (idx + j < n) v[j] = cnt[idx + j];
    }
    red[t] = v[0] + v[1] + v[2] + v[3];
    __syncthreads();
    for (int off = 1; off < 256; off <<= 1) {
        int x = (t >= off) ? red[t - off] : 0;
        __syncthreads();
        red[t] += x;
        __syncthreads();
    }
    int run = ((t == 0) ? 0 : red[t - 1]) + boff[blockIdx.x];
    #pragma unroll
    for (int j = 0; j < 4; ++j) {
        if (idx + j < n) {
            rp[idx + j] = run;
            dinv[idx + j] = rsqrtf((float)(v[j] + 1));  // +1 self-loop
            run += v[j];
        }
    }
}

static __global__ __launch_bounds__(256) void k_scatter(const int* __restrict__ rows,
                                                        const int* __restrict__ cols,
                                                        const int* __restrict__ rp,
                                                        int* __restrict__ fill,
                                                        const float* __restrict__ dinv,
                                                        int2* __restrict__ colw, int E)
{
    int i = blockIdx.x * 256 + threadIdx.x;
    if (i < E) {
        int r = rows[i], c = cols[i];
        int pos = rp[r] + atomicAdd(&fill[r], 1);
        colw[pos] = make_int2(c, __float_as_int(dinv[c]));
    }
}

// ---------------- init: y = 0.5*x (f32) ; h = bf16(0.5*x), split into 2 feature halves ----
// h layout (u32 view): [half][row][16 u32]  (each half-row = 32 bf16 = 64B line)

static __global__ __launch_bounds__(256) void k_init(const float4* __restrict__ x4,
                                                     float4* __restrict__ y4,
                                                     uint4* __restrict__ h, int nchunk, int n)
{
    int i = blockIdx.x * 256 + threadIdx.x;
    if (i >= nchunk) return;                  // i = row*8 + q ; q = half*4 + slot
    float4 a = x4[i * 2], b = x4[i * 2 + 1];
    a.x *= 0.5f; a.y *= 0.5f; a.z *= 0.5f; a.w *= 0.5f;
    b.x *= 0.5f; b.y *= 0.5f; b.z *= 0.5f; b.w *= 0.5f;
    y4[i * 2] = a; y4[i * 2 + 1] = b;
    int row = i >> 3, q = i & 7;
    int half = q >> 2, slot = q & 3;
    h[(size_t)half * n * 4 + (size_t)row * 4 + slot] =
        make_uint4(packbf(a.x, a.y), packbf(a.z, a.w),
                   packbf(b.x, b.y), packbf(b.z, b.w));
}

// ---------------- SpMM: feature-split halves, 4 rows/wave, 16 lanes x u32 per row ----
// half = blockIdx&1 -> even/odd XCDs each see only a 6.4MB gather set (L2 locality).
// ACC iterations fold y += h_k (self-loop value, already loaded) + h_{k+1}.

template<bool ACC>
static __global__ __launch_bounds__(256) void k_spmm(const unsigned* __restrict__ hcur,
                                                     unsigned* __restrict__ hnxt,
                                                     float2* __restrict__ y2,
                                                     const int* __restrict__ rp,
                                                     const int2* __restrict__ colw,
                                                     const float* __restrict__ dinv, int n)
{
    int half = blockIdx.x & 1;
    int lane = threadIdx.x & 63;
    int wv   = threadIdx.x >> 6;
    int row  = (blockIdx.x >> 1) * 16 + wv * 4 + (lane >> 4);
    int j    = lane & 15;              // u32 slot (2 bf16 feats) within 64B half-row
    if (row >= n) return;
    const unsigned* hb = hcur + (size_t)half * n * 16;
    unsigned*       ho = hnxt + (size_t)half * n * 16;
    int s = rp[row], e = rp[row + 1];

    float aL = 0.f, aR = 0.f, bL = 0.f, bR = 0.f;
    int i = s;
    for (; i + 3 < e; i += 4) {
        int2 c0 = colw[i], c1 = colw[i + 1], c2 = colw[i + 2], c3 = colw[i + 3];
        unsigned h0 = hb[(size_t)c0.x * 16 + j];
        unsigned h1 = hb[(size_t)c1.x * 16 + j];
        unsigned h2 = hb[(size_t)c2.x * 16 + j];
        unsigned h3 = hb[(size_t)c3.x * 16 + j];
        float w0 = __int_as_float(c0.y), w1 = __int_as_float(c1.y);
        float w2 = __int_as_float(c2.y), w3 = __int_as_float(c3.y);
        aL = fmaf(w0, bflo(h0), aL); aR = fmaf(w0, bfhi(h0), aR);
        bL = fmaf(w1, bflo(h1), bL); bR = fmaf(w1, bfhi(h1), bR);
        aL = fmaf(w2, bflo(h2), aL); aR = fmaf(w2, bfhi(h2), aR);
        bL = fmaf(w3, bflo(h3), bL); bR = fmaf(w3, bfhi(h3), bR);
    }
    for (; i < e; ++i) {
        int2 c = colw[i];
        unsigned h = hb[(size_t)c.x * 16 + j];
        float w = __int_as_float(c.y);
        aL = fmaf(w, bflo(h), aL); aR = fmaf(w, bfhi(h), aR);
    }
    float accL = aL + bL, accR = aR + bR;

    float di = dinv[row];
    unsigned hsv = hb[(size_t)row * 16 + j];
    float hsL = bflo(hsv), hsR = bfhi(hsv);
    float v0 = di * fmaf(di, hsL, accL);
    float v1 = di * fmaf(di, hsR, accR);
    ho[(size_t)row * 16 + j] = packbf(v0, v1);
    if (ACC) {
        size_t yi = (size_t)row * 32 + half * 16 + j;
        float2 yv = y2[yi];
        yv.x += hsL + v0;     // h_k + h_{k+1}
        yv.y += hsR + v1;
        y2[yi] = yv;
    }
}

// ---------------- fused MLP: 64 rows/block, LDS-staged, broadcast weights (unchanged) ----

static __global__ __launch_bounds__(256) void k_mlp(const float4* __restrict__ y4,
                                                    const float* __restrict__ W1,
                                                    const float* __restrict__ b1,
                                                    const float* __restrict__ W2,
                                                    const float* __restrict__ b2,
                                                    float* __restrict__ out, int n)
{
    __shared__ float ysT[64][68];          // [feat][row], f32
    __shared__ unsigned short hs[64][268]; // [row][hid] bf16
    const float S = 1.f / 9.f;
    int t = threadIdx.x;
    int base = blockIdx.x * 64;

    {
        int r = t >> 2, fq = t & 3;
        int row = base + r;
        bool valid = row < n;
        #pragma unroll
        for (int j = 0; j < 4; ++j) {
            float4 v = valid ? y4[(size_t)row * 16 + fq * 4 + j]
                             : make_float4(0.f, 0.f, 0.f, 0.f);
            ysT[fq * 16 + j * 4 + 0][r] = v.x * S;
            ysT[fq * 16 + j * 4 + 1][r] = v.y * S;
            ysT[fq * 16 + j * 4 + 2][r] = v.z * S;
            ysT[fq * 16 + j * 4 + 3][r] = v.w * S;
        }
    }
    __syncthreads();

    int c = t & 63;
    int w = t >> 6;
    int w16 = w * 16;
    {
        float4 acc[16];
        float4 bb = ((const float4*)b1)[c];
        #pragma unroll
        for (int r = 0; r < 16; ++r) acc[r] = bb;
        const float4* W14 = (const float4*)W1;
        #pragma unroll 2
        for (int k = 0; k < 64; ++k) {
            float4 wv = W14[k * 64 + c];
            const float4* yp = (const float4*)&ysT[k][w16];
            float4 y0 = yp[0], y1 = yp[1], y2 = yp[2], y3 = yp[3];
            #pragma unroll
            for (int j = 0; j < 4; ++j) {
                float ya = (j == 0) ? y0.x : (j == 1) ? y0.y : (j == 2) ? y0.z : y0.w;
                acc[j].x = fmaf(ya, wv.x, acc[j].x);
                acc[j].y = fmaf(ya, wv.y, acc[j].y);
                acc[j].z = fmaf(ya, wv.z, acc[j].z);
                acc[j].w = fmaf(ya, wv.w, acc[j].w);
            }
            #pragma unroll
            for (int j = 0; j < 4; ++j) {
                float ya = (j == 0) ? y1.x : (j == 1) ? y1.y : (j == 2) ? y1.z : y1.w;
                acc[4 + j].x = fmaf(ya, wv.x, acc[4 + j].x);
                acc[4 + j].y = fmaf(ya, wv.y, acc[4 + j].y);
                acc[4 + j].z = fmaf(ya, wv.z, acc[4 + j].z);
                acc[4 + j].w = fmaf(ya, wv.w, acc[4 + j].w);
            }
            #pragma unroll
            for (int j = 0; j < 4; ++j) {
                float ya = (j == 0) ? y2.x : (j == 1) ? y2.y : (j == 2) ? y2.z : y2.w;
                acc[8 + j].x = fmaf(ya, wv.x, acc[8 + j].x);
                acc[8 + j].y = fmaf(ya, wv.y, acc[8 + j].y);
                acc[8 + j].z = fmaf(ya, wv.z, acc[8 + j].z);
                acc[8 + j].w = fmaf(ya, wv.w, acc[8 + j].w);
            }
            #pragma unroll
            for (int j = 0; j < 4; ++j) {
                float ya = (j == 0) ? y3.x : (j == 1) ? y3.y : (j == 2) ? y3.z : y3.w;
                acc[12 + j].x = fmaf(ya, wv.x, acc[12 + j].x);
                acc[12 + j].y = fmaf(ya, wv.y, acc[12 + j].y);
                acc[12 + j].z = fmaf(ya, wv.z, acc[12 + j].z);
                acc[12 + j].w = fmaf(ya, wv.w, acc[12 + j].w);
            }
        }
        #pragma unroll
        for (int r = 0; r < 16; ++r) {
            float hx = fmaxf(acc[r].x, 0.f), hy = fmaxf(acc[r].y, 0.f);
            float hz = fmaxf(acc[r].z, 0.f), hw = fmaxf(acc[r].w, 0.f);
            uint2 p = make_uint2(packbf(hx, hy), packbf(hz, hw));
            *(uint2*)&hs[w16 + r][c * 4] = p;
        }
    }
    __syncthreads();

    {
        int r2 = t & 63;
        int wj = __builtin_amdgcn_readfirstlane(t >> 6);
        int row = base + r2;
        float o[10];
        #pragma unroll
        for (int j = 0; j < 10; ++j) o[j] = b2[wj * 10 + j];
        #pragma unroll 2
        for (int k4 = 0; k4 < 64; ++k4) {
            uint2 hv = *(const uint2*)&hs[r2][k4 * 4];
            float h0 = bflo(hv.x), h1 = bfhi(hv.x);
            float h2 = bflo(hv.y), h3 = bfhi(hv.y);
            const float* w2p = W2 + (k4 * 4) * NC + wj * 10;
            #pragma unroll
            for (int j = 0; j < 10; ++j) o[j] = fmaf(h0, w2p[j], o[j]);
            #pragma unroll
            for (int j = 0; j < 10; ++j) o[j] = fmaf(h1, w2p[NC + j], o[j]);
            #pragma unroll
            for (int j = 0; j < 10; ++j) o[j] = fmaf(h2, w2p[2 * NC + j], o[j]);
            #pragma unroll
            for (int j = 0; j < 10; ++j) o[j] = fmaf(h3, w2p[3 * NC + j], o[j]);
        }
        if (row < n) {
            float* op = out + (size_t)row * NC + wj * 10;
            #pragma unroll
            for (int j = 0; j < 5; ++j)
                *(float2*)(op + j * 2) = make_float2(o[j * 2], o[j * 2 + 1]);
        }
    }
}

// ---------------- launch ----------------

extern "C" void kernel_launch(void* const* d_in, const int* in_sizes, int n_in,
                              void* d_out, int out_size, void* d_ws, size_t ws_size,
                              hipStream_t stream)
{
    const float* x  = (const float*)d_in[0];
    const int*   ei = (const int*)d_in[1];
    const float* W1 = (const float*)d_in[2];
    const float* b1 = (const float*)d_in[3];
    const float* W2 = (const float*)d_in[4];
    const float* b2 = (const float*)d_in[5];
    float* out = (float*)d_out;

    const int n = NN, E = NE;
    const int nb = (n + SC - 1) / SC;  // 98 scan blocks

    char* ws = (char*)d_ws;
    size_t off = 0;
    auto alloc = [&](size_t bytes) -> void* {
        void* p = ws + off;
        off = (off + bytes + 255) & ~(size_t)255;
        return p;
    };
    int*   cnt  = (int*)  alloc((size_t)n * 4);
    int*   fill = (int*)  alloc((size_t)n * 4);
    int*   rp   = (int*)  alloc((size_t)(n + 1) * 4);
    float* dinv = (float*)alloc((size_t)n * 4);
    int*   bsum = (int*)  alloc(128 * 4);
    int*   boff = (int*)  alloc(128 * 4);
    int2*  colw = (int2*) alloc((size_t)E * 8);
    unsigned* hping = (unsigned*)alloc((size_t)n * 32 * 4);  // [2 halves][n][16 u32]
    unsigned* hpong = (unsigned*)alloc((size_t)n * 32 * 4);
    float* y    = (float*)alloc((size_t)n * NF * 4);         // f32 accumulator

    hipMemsetAsync(cnt, 0, (size_t)n * 4, stream);
    hipMemsetAsync(fill, 0, (size_t)n * 4, stream);

    const int* rows = ei;
    const int* cols = ei + E;

    k_count  <<<(E + 255) / 256, 256, 0, stream>>>(rows, cnt, E);
    k_bsum   <<<nb, 256, 0, stream>>>(cnt, bsum, n);
    k_scanb  <<<1, 128, 0, stream>>>(bsum, boff, rp, nb, n);
    k_scan3  <<<nb, 256, 0, stream>>>(cnt, boff, rp, dinv, n);
    k_scatter<<<(E + 255) / 256, 256, 0, stream>>>(rows, cols, rp, fill, dinv, colw, E);

    int nchunk = n * 8;
    k_init<<<(nchunk + 255) / 256, 256, 0, stream>>>((const float4*)x, (float4*)y,
                                                     (uint4*)hping, nchunk, n);

    unsigned* cur = hping;
    unsigned* nxt = hpong;
    int spmm_blocks = 2 * ((n + 15) / 16);   // 12500: half = blockIdx&1
    for (int it = 0; it < ORDER_C; ++it) {
        if (it & 1)
            k_spmm<true><<<spmm_blocks, 256, 0, stream>>>(cur, nxt, (float2*)y,
                                                          rp, colw, dinv, n);
        else
            k_spmm<false><<<spmm_blocks, 256, 0, stream>>>(cur, nxt, (float2*)y,
                                                           rp, colw, dinv, n);
        unsigned* t = cur; cur = nxt; nxt = t;
    }

    k_mlp<<<(n + 63) / 64, 256, 0, stream>>>((const float4*)y, W1, b1, W2, b2, out, n);
}

// Round 7
// 474.086 us; speedup vs baseline: 1.2396x; 1.2396x over previous
//
#include <hip/hip_runtime.h>

#define NN 100000
#define NE 1200000
#define NF 64
#define NH 256
#define NC 40
#define ORDER_C 8
#define SC 1024  // scan chunk (elements per block)

typedef __attribute__((ext_vector_type(8))) short short8;
typedef __attribute__((ext_vector_type(4))) float f32x4;

// ---- bf16 helpers (RTNE pack, cheap unpack) ----
__device__ __forceinline__ unsigned bf16r(float x) {
    unsigned u = __float_as_uint(x);
    return (u + 0x7FFFu + ((u >> 16) & 1u)) >> 16;
}
__device__ __forceinline__ unsigned packbf(float lo, float hi) {
    return bf16r(lo) | (bf16r(hi) << 16);
}
__device__ __forceinline__ float bflo(unsigned u) { return __uint_as_float(u << 16); }
__device__ __forceinline__ float bfhi(unsigned u) { return __uint_as_float(u & 0xFFFF0000u); }

// ---------------- CSR build ----------------

static __global__ __launch_bounds__(256) void k_count(const int* __restrict__ rows,
                                                      int* __restrict__ cnt, int E)
{
    int i = blockIdx.x * 256 + threadIdx.x;
    if (i < E) atomicAdd(&cnt[rows[i]], 1);
}

static __global__ __launch_bounds__(256) void k_bsum(const int* __restrict__ cnt,
                                                     int* __restrict__ bsum, int n)
{
    __shared__ int red[256];
    int t = threadIdx.x;
    int idx = blockIdx.x * SC + t * 4;
    int s = 0;
    if (idx + 3 < n) {
        int4 q = *(const int4*)&cnt[idx];
        s = q.x + q.y + q.z + q.w;
    } else {
        for (int j = 0; j < 4; ++j) if (idx + j < n) s += cnt[idx + j];
    }
    red[t] = s;
    __syncthreads();
    for (int off = 128; off > 0; off >>= 1) {
        if (t < off) red[t] += red[t + off];
        __syncthreads();
    }
    if (t == 0) bsum[blockIdx.x] = red[0];
}

static __global__ __launch_bounds__(128) void k_scanb(const int* __restrict__ bsum,
                                                      int* __restrict__ boff,
                                                      int* __restrict__ rp, int nb, int n)
{
    __shared__ int red[128];
    int t = threadIdx.x;
    int v = (t < nb) ? bsum[t] : 0;
    red[t] = v;
    __syncthreads();
    for (int off = 1; off < 128; off <<= 1) {
        int x = (t >= off) ? red[t - off] : 0;
        __syncthreads();
        red[t] += x;
        __syncthreads();
    }
    if (t < nb) boff[t] = (t == 0) ? 0 : red[t - 1];
    if (t == 0) rp[n] = red[127];
}

static __global__ __launch_bounds__(256) void k_scan3(const int* __restrict__ cnt,
                                                      const int* __restrict__ boff,
                                                      int* __restrict__ rp,
                                                      float* __restrict__ dinv, int n)
{
    __shared__ int red[256];
    int t = threadIdx.x;
    int idx = blockIdx.x * SC + t * 4;
    int v[4] = {0, 0, 0, 0};
    if (idx + 3 < n) {
        int4 q = *(const int4*)&cnt[idx];
        v[0] = q.x; v[1] = q.y; v[2] = q.z; v[3] = q.w;
    } else {
        for (int j = 0; j < 4; ++j) if (idx + j < n) v[j] = cnt[idx + j];
    }
    red[t] = v[0] + v[1] + v[2] + v[3];
    __syncthreads();
    for (int off = 1; off < 256; off <<= 1) {
        int x = (t >= off) ? red[t - off] : 0;
        __syncthreads();
        red[t] += x;
        __syncthreads();
    }
    int run = ((t == 0) ? 0 : red[t - 1]) + boff[blockIdx.x];
    #pragma unroll
    for (int j = 0; j < 4; ++j) {
        if (idx + j < n) {
            rp[idx + j] = run;
            dinv[idx + j] = rsqrtf((float)(v[j] + 1));  // +1 self-loop
            run += v[j];
        }
    }
}

static __global__ __launch_bounds__(256) void k_scatter(const int* __restrict__ rows,
                                                        const int* __restrict__ cols,
                                                        const int* __restrict__ rp,
                                                        int* __restrict__ fill,
                                                        const float* __restrict__ dinv,
                                                        int2* __restrict__ colw, int E)
{
    int i = blockIdx.x * 256 + threadIdx.x;
    if (i < E) {
        int r = rows[i], c = cols[i];
        int pos = rp[r] + atomicAdd(&fill[r], 1);
        colw[pos] = make_int2(c, __float_as_int(dinv[c]));
    }
}

// ---------------- pack W1/W2 into MFMA B-fragment order (bf16) ----------------
// kappa(g,e) = 8g + e  (same bijection used for ALL A and B fragments)
// w1f entry (s*16+nt)*64+lane : W1[32s + kappa][16nt + (lane&15)]
// w2f entry (s*3 +nt)*64+lane : W2[32s + kappa][16nt + (lane&15)] (0 if col>=40)

static __global__ __launch_bounds__(256) void k_pack(const float* __restrict__ W1,
                                                     const float* __restrict__ W2,
                                                     unsigned short* __restrict__ w1f,
                                                     unsigned short* __restrict__ w2f)
{
    int t = blockIdx.x * 256 + threadIdx.x;
    if (t < 2048) {
        int lane = t & 63;
        int g = lane >> 4, col = (lane & 15) + ((t >> 6) & 15) * 16;
        int s = t >> 10;
        unsigned short* p = w1f + (size_t)t * 8;
        #pragma unroll
        for (int e = 0; e < 8; ++e) {
            int k = 32 * s + 8 * g + e;
            p[e] = (unsigned short)bf16r(W1[k * NH + col]);
        }
    } else if (t < 2048 + 1536) {
        int u = t - 2048;
        int lane = u & 63;
        int tile = u >> 6;
        int nt = tile % 3, s = tile / 3;
        int g = lane >> 4, col = (lane & 15) + nt * 16;
        unsigned short* p = w2f + (size_t)u * 8;
        #pragma unroll
        for (int e = 0; e < 8; ++e) {
            int k = 32 * s + 8 * g + e;
            p[e] = (col < NC) ? (unsigned short)bf16r(W2[k * NC + col]) : 0;
        }
    }
}

// ---------------- init: y = 0.5*x (f32) ; h = bf16(0.5*x) ----------------

static __global__ __launch_bounds__(256) void k_init(const float4* __restrict__ x4,
                                                     float4* __restrict__ y4,
                                                     uint4* __restrict__ hb, int nchunk)
{
    int i = blockIdx.x * 256 + threadIdx.x;
    if (i >= nchunk) return;
    float4 a = x4[i * 2], b = x4[i * 2 + 1];
    a.x *= 0.5f; a.y *= 0.5f; a.z *= 0.5f; a.w *= 0.5f;
    b.x *= 0.5f; b.y *= 0.5f; b.z *= 0.5f; b.w *= 0.5f;
    y4[i * 2] = a; y4[i * 2 + 1] = b;
    hb[i] = make_uint4(packbf(a.x, a.y), packbf(a.z, a.w),
                       packbf(b.x, b.y), packbf(b.z, b.w));
}

// ---------------- SpMM: half-wave per row, lane = u32 (2 bf16 feats) ----------------
// ACC iterations fold y += h_k (self-loop value, already loaded) + h_{k+1}.

template<bool ACC>
static __global__ __launch_bounds__(256) void k_spmm(const unsigned* __restrict__ hb,
                                                     unsigned* __restrict__ ho,
                                                     float2* __restrict__ y2,
                                                     const int* __restrict__ rp,
                                                     const int2* __restrict__ colw,
                                                     const float* __restrict__ dinv, int n)
{
    int wid  = (blockIdx.x * 256 + threadIdx.x) >> 6;
    int lane = threadIdx.x & 63;
    int row  = wid * 2 + (lane >> 5);
    int j    = lane & 31;            // u32 slot within the 128B bf16 row
    if (row >= n) return;
    int s = rp[row], e = rp[row + 1];

    float aL0 = 0.f, aR0 = 0.f, aL1 = 0.f, aR1 = 0.f;
    int i = s;
    for (; i + 3 < e; i += 4) {
        int2 c0 = colw[i], c1 = colw[i + 1], c2 = colw[i + 2], c3 = colw[i + 3];
        unsigned h0 = hb[c0.x * 32 + j];
        unsigned h1 = hb[c1.x * 32 + j];
        unsigned h2 = hb[c2.x * 32 + j];
        unsigned h3 = hb[c3.x * 32 + j];
        float w0 = __int_as_float(c0.y), w1 = __int_as_float(c1.y);
        float w2 = __int_as_float(c2.y), w3 = __int_as_float(c3.y);
        aL0 = fmaf(w0, bflo(h0), aL0); aR0 = fmaf(w0, bfhi(h0), aR0);
        aL1 = fmaf(w1, bflo(h1), aL1); aR1 = fmaf(w1, bfhi(h1), aR1);
        aL0 = fmaf(w2, bflo(h2), aL0); aR0 = fmaf(w2, bfhi(h2), aR0);
        aL1 = fmaf(w3, bflo(h3), aL1); aR1 = fmaf(w3, bfhi(h3), aR1);
    }
    for (; i < e; ++i) {
        int2 c = colw[i];
        unsigned h = hb[c.x * 32 + j];
        float w = __int_as_float(c.y);
        aL0 = fmaf(w, bflo(h), aL0); aR0 = fmaf(w, bfhi(h), aR0);
    }
    float accL = aL0 + aL1, accR = aR0 + aR1;

    float di = dinv[row];
    unsigned hsv = hb[row * 32 + j];
    float hsL = bflo(hsv), hsR = bfhi(hsv);
    float v0 = di * fmaf(di, hsL, accL);
    float v1 = di * fmaf(di, hsR, accR);
    ho[row * 32 + j] = packbf(v0, v1);
    if (ACC) {
        float2 yv = y2[row * 32 + j];
        yv.x += hsL + v0;     // h_k + h_{k+1}
        yv.y += hsR + v1;
        y2[row * 32 + j] = yv;
    }
}

// ---------------- MFMA MLP: 64 rows/block, 4 waves ----------------
// out[row] = relu((y[row]/9) @ W1 + b1) @ W2 + b2
// A/B fragments both use kappa(g,e)=8g+e (correct for any true within-group
// ordering since the same bijection feeds both operands). C/D layout is the
// verified col=lane&15, row=4*(lane>>4)+reg.

#define YSTR 72    // shorts per ys row (144B, 16B-aligned, conflict-benign)
#define HSTR 264   // shorts per hs row (528B, 16B-aligned)

static __global__ __launch_bounds__(256) void k_mlp(const float4* __restrict__ y4,
                                                    const short8* __restrict__ w1f,
                                                    const short8* __restrict__ w2f,
                                                    const float* __restrict__ b1,
                                                    const float* __restrict__ b2,
                                                    float* __restrict__ out, int n)
{
    __shared__ short lds[64 * HSTR];   // 33.8 KB; first 64*YSTR shorts = ys
    int t = threadIdx.x;
    int lane = t & 63;
    int w = t >> 6;
    int base = blockIdx.x * 64;
    const float S = 1.f / 9.f;

    // ---- stage ys: y rows -> bf16, scaled ----
    {
        int r = t >> 2, q = t & 3;     // 4 threads/row, 16 feats each
        int row = base + r;
        unsigned v[8];
        if (row < n) {
            const float4* yp = y4 + (size_t)row * 16 + q * 4;
            #pragma unroll
            for (int i = 0; i < 4; ++i) {
                float4 f = yp[i];
                v[i * 2]     = packbf(f.x * S, f.y * S);
                v[i * 2 + 1] = packbf(f.z * S, f.w * S);
            }
        } else {
            #pragma unroll
            for (int i = 0; i < 8; ++i) v[i] = 0;
        }
        uint4* dst = (uint4*)&lds[r * YSTR + q * 16];
        dst[0] = make_uint4(v[0], v[1], v[2], v[3]);
        dst[1] = make_uint4(v[4], v[5], v[6], v[7]);
    }
    __syncthreads();

    int m = lane & 15, g = lane >> 4;

    // ---- layer 1: H[64,256] = ys @ W1 + b1 ----
    f32x4 acc[4][4];   // [mt][nt4]
    {
        short8 a[4][2];
        #pragma unroll
        for (int mt = 0; mt < 4; ++mt)
            #pragma unroll
            for (int s = 0; s < 2; ++s)
                a[mt][s] = *(const short8*)&lds[(mt * 16 + m) * YSTR + s * 32 + g * 8];
        #pragma unroll
        for (int nt4 = 0; nt4 < 4; ++nt4) {
            int nt = w * 4 + nt4;
            short8 b0  = w1f[nt * 64 + lane];
            short8 b1v = w1f[(16 + nt) * 64 + lane];
            float bias = b1[nt * 16 + m];
            #pragma unroll
            for (int mt = 0; mt < 4; ++mt) {
                f32x4 c = {bias, bias, bias, bias};
                c = __builtin_amdgcn_mfma_f32_16x16x32_bf16(a[mt][0], b0,  c, 0, 0, 0);
                c = __builtin_amdgcn_mfma_f32_16x16x32_bf16(a[mt][1], b1v, c, 0, 0, 0);
                acc[mt][nt4] = c;
            }
        }
    }
    __syncthreads();   // all ys reads complete; reuse lds as hs

    // ---- relu + bf16 -> hs ----
    {
        #pragma unroll
        for (int mt = 0; mt < 4; ++mt)
            #pragma unroll
            for (int nt4 = 0; nt4 < 4; ++nt4) {
                int col = w * 64 + nt4 * 16 + m;
                #pragma unroll
                for (int r = 0; r < 4; ++r) {
                    float hv = fmaxf(acc[mt][nt4][r], 0.f);
                    lds[(mt * 16 + g * 4 + r) * HSTR + col] = (short)bf16r(hv);
                }
            }
    }
    __syncthreads();

    // ---- layer 2: wave w -> rows 16w..16w+15 ; Out = hs @ W2 + b2 ----
    {
        short8 a2[8];
        #pragma unroll
        for (int s = 0; s < 8; ++s)
            a2[s] = *(const short8*)&lds[(w * 16 + m) * HSTR + s * 32 + g * 8];
        #pragma unroll
        for (int nt = 0; nt < 3; ++nt) {
            int col = nt * 16 + m;
            float bias = (col < NC) ? b2[col] : 0.f;
            f32x4 c = {bias, bias, bias, bias};
            #pragma unroll
            for (int s = 0; s < 8; ++s)
                c = __builtin_amdgcn_mfma_f32_16x16x32_bf16(a2[s], w2f[(s * 3 + nt) * 64 + lane], c, 0, 0, 0);
            if (col < NC) {
                #pragma unroll
                for (int r = 0; r < 4; ++r) {
                    int row = base + w * 16 + g * 4 + r;
                    if (row < n) out[(size_t)row * NC + col] = c[r];
                }
            }
        }
    }
}

// ---------------- launch ----------------

extern "C" void kernel_launch(void* const* d_in, const int* in_sizes, int n_in,
                              void* d_out, int out_size, void* d_ws, size_t ws_size,
                              hipStream_t stream)
{
    const float* x  = (const float*)d_in[0];
    const int*   ei = (const int*)d_in[1];
    const float* W1 = (const float*)d_in[2];
    const float* b1 = (const float*)d_in[3];
    const float* W2 = (const float*)d_in[4];
    const float* b2 = (const float*)d_in[5];
    float* out = (float*)d_out;

    const int n = NN, E = NE;
    const int nb = (n + SC - 1) / SC;  // 98 scan blocks

    char* ws = (char*)d_ws;
    size_t off = 0;
    auto alloc = [&](size_t bytes) -> void* {
        void* p = ws + off;
        off = (off + bytes + 255) & ~(size_t)255;
        return p;
    };
    int*   cnt  = (int*)  alloc((size_t)n * 4);
    int*   fill = (int*)  alloc((size_t)n * 4);
    int*   rp   = (int*)  alloc((size_t)(n + 1) * 4);
    float* dinv = (float*)alloc((size_t)n * 4);
    int*   bsum = (int*)  alloc(128 * 4);
    int*   boff = (int*)  alloc(128 * 4);
    int2*  colw = (int2*) alloc((size_t)E * 8);
    unsigned short* w1f = (unsigned short*)alloc(2048 * 8 * 2);
    unsigned short* w2f = (unsigned short*)alloc(1536 * 8 * 2);
    uint4* ha   = (uint4*)alloc((size_t)n * NF * 2);   // bf16 h ping
    uint4* hbuf = (uint4*)alloc((size_t)n * NF * 2);   // bf16 h pong
    float* y    = (float*)alloc((size_t)n * NF * 4);   // f32 accumulator

    hipMemsetAsync(cnt, 0, (size_t)n * 4, stream);
    hipMemsetAsync(fill, 0, (size_t)n * 4, stream);

    const int* rows = ei;
    const int* cols = ei + E;

    k_count  <<<(E + 255) / 256, 256, 0, stream>>>(rows, cnt, E);
    k_bsum   <<<nb, 256, 0, stream>>>(cnt, bsum, n);
    k_scanb  <<<1, 128, 0, stream>>>(bsum, boff, rp, nb, n);
    k_scan3  <<<nb, 256, 0, stream>>>(cnt, boff, rp, dinv, n);
    k_scatter<<<(E + 255) / 256, 256, 0, stream>>>(rows, cols, rp, fill, dinv, colw, E);
    k_pack   <<<14, 256, 0, stream>>>(W1, W2, w1f, w2f);

    int nchunk = n * 8;
    k_init<<<(nchunk + 255) / 256, 256, 0, stream>>>((const float4*)x, (float4*)y,
                                                     ha, nchunk);

    uint4* cur = ha;
    uint4* nxt = hbuf;
    int spmm_blocks = ((size_t)n * 32 + 255) / 256;   // 12500
    for (int it = 0; it < ORDER_C; ++it) {
        if (it & 1)
            k_spmm<true><<<spmm_blocks, 256, 0, stream>>>((const unsigned*)cur, (unsigned*)nxt,
                                                          (float2*)y, rp, colw, dinv, n);
        else
            k_spmm<false><<<spmm_blocks, 256, 0, stream>>>((const unsigned*)cur, (unsigned*)nxt,
                                                           (float2*)y, rp, colw, dinv, n);
        uint4* tswap = cur; cur = nxt; nxt = tswap;
    }

    k_mlp<<<(n + 63) / 64, 256, 0, stream>>>((const float4*)y, (const short8*)w1f,
                                             (const short8*)w2f, b1, b2, out, n);
}

// Round 8
// 466.086 us; speedup vs baseline: 1.2609x; 1.0172x over previous
//
#include <hip/hip_runtime.h>

#define NN 100000
#define NE 1200000
#define NF 64
#define NH 256
#define NC 40
#define ORDER_C 8
#define SC 1024  // scan chunk (elements per block)

typedef __attribute__((ext_vector_type(8))) short short8;
typedef __attribute__((ext_vector_type(4))) float f32x4;

// ---- bf16 helpers (RTNE pack, cheap unpack) ----
__device__ __forceinline__ unsigned bf16r(float x) {
    unsigned u = __float_as_uint(x);
    return (u + 0x7FFFu + ((u >> 16) & 1u)) >> 16;
}
__device__ __forceinline__ unsigned packbf(float lo, float hi) {
    return bf16r(lo) | (bf16r(hi) << 16);
}
__device__ __forceinline__ float bflo(unsigned u) { return __uint_as_float(u << 16); }
__device__ __forceinline__ float bfhi(unsigned u) { return __uint_as_float(u & 0xFFFF0000u); }

// ---------------- CSR build ----------------

static __global__ __launch_bounds__(256) void k_count(const int* __restrict__ rows,
                                                      int* __restrict__ cnt, int E)
{
    int i = blockIdx.x * 256 + threadIdx.x;
    if (i < E) atomicAdd(&cnt[rows[i]], 1);
}

static __global__ __launch_bounds__(256) void k_bsum(const int* __restrict__ cnt,
                                                     int* __restrict__ bsum, int n)
{
    __shared__ int red[256];
    int t = threadIdx.x;
    int idx = blockIdx.x * SC + t * 4;
    int s = 0;
    if (idx + 3 < n) {
        int4 q = *(const int4*)&cnt[idx];
        s = q.x + q.y + q.z + q.w;
    } else {
        for (int j = 0; j < 4; ++j) if (idx + j < n) s += cnt[idx + j];
    }
    red[t] = s;
    __syncthreads();
    for (int off = 128; off > 0; off >>= 1) {
        if (t < off) red[t] += red[t + off];
        __syncthreads();
    }
    if (t == 0) bsum[blockIdx.x] = red[0];
}

static __global__ __launch_bounds__(128) void k_scanb(const int* __restrict__ bsum,
                                                      int* __restrict__ boff,
                                                      int* __restrict__ rp, int nb, int n)
{
    __shared__ int red[128];
    int t = threadIdx.x;
    int v = (t < nb) ? bsum[t] : 0;
    red[t] = v;
    __syncthreads();
    for (int off = 1; off < 128; off <<= 1) {
        int x = (t >= off) ? red[t - off] : 0;
        __syncthreads();
        red[t] += x;
        __syncthreads();
    }
    if (t < nb) boff[t] = (t == 0) ? 0 : red[t - 1];
    if (t == 0) rp[n] = red[127];
}

// scan phase 3: rp + packed (dinv, rd) per row
static __global__ __launch_bounds__(256) void k_scan3(const int* __restrict__ cnt,
                                                      const int* __restrict__ boff,
                                                      int* __restrict__ rp,
                                                      float2* __restrict__ drd, int n)
{
    __shared__ int red[256];
    int t = threadIdx.x;
    int idx = blockIdx.x * SC + t * 4;
    int v[4] = {0, 0, 0, 0};
    if (idx + 3 < n) {
        int4 q = *(const int4*)&cnt[idx];
        v[0] = q.x; v[1] = q.y; v[2] = q.z; v[3] = q.w;
    } else {
        for (int j = 0; j < 4; ++j) if (idx + j < n) v[j] = cnt[idx + j];
    }
    red[t] = v[0] + v[1] + v[2] + v[3];
    __syncthreads();
    for (int off = 1; off < 256; off <<= 1) {
        int x = (t >= off) ? red[t - off] : 0;
        __syncthreads();
        red[t] += x;
        __syncthreads();
    }
    int run = ((t == 0) ? 0 : red[t - 1]) + boff[blockIdx.x];
    #pragma unroll
    for (int j = 0; j < 4; ++j) {
        if (idx + j < n) {
            rp[idx + j] = run;
            float d1 = rsqrtf((float)(v[j] + 1));          // 1/sqrt(deg)
            drd[idx + j] = make_float2(d1, (float)(v[j] + 1) * d1);  // (dinv, sqrt(deg))
            run += v[j];
        }
    }
}

// XCD-partitioned scatter: group g = blockIdx&7 owns rows [g*NN/8, (g+1)*NN/8).
// With round-robin block->XCD dispatch, each XCD fills a disjoint ccol region
// from its own L2 (full-line writeback, L2-local fill atomics).
static __global__ __launch_bounds__(256) void k_scatter(const int* __restrict__ rows,
                                                        const int* __restrict__ cols,
                                                        const int* __restrict__ rp,
                                                        int* __restrict__ fill,
                                                        int* __restrict__ ccol, int E)
{
    int grp = blockIdx.x & 7;
    int lo = grp * (NN / 8), hi = lo + (NN / 8);
    int stride = (gridDim.x >> 3) * 256;
    for (int i = (blockIdx.x >> 3) * 256 + threadIdx.x; i < E; i += stride) {
        int r = rows[i];
        if (r >= lo && r < hi) {
            int pos = rp[r] + atomicAdd(&fill[r], 1);
            ccol[pos] = cols[i];
        }
    }
}

// ---------------- pack W1/W2 into MFMA B-fragment order (bf16) ----------------

static __global__ __launch_bounds__(256) void k_pack(const float* __restrict__ W1,
                                                     const float* __restrict__ W2,
                                                     unsigned short* __restrict__ w1f,
                                                     unsigned short* __restrict__ w2f)
{
    int t = blockIdx.x * 256 + threadIdx.x;
    if (t < 2048) {
        int lane = t & 63;
        int g = lane >> 4, col = (lane & 15) + ((t >> 6) & 15) * 16;
        int s = t >> 10;
        unsigned short* p = w1f + (size_t)t * 8;
        #pragma unroll
        for (int e = 0; e < 8; ++e) {
            int k = 32 * s + 8 * g + e;
            p[e] = (unsigned short)bf16r(W1[k * NH + col]);
        }
    } else if (t < 2048 + 1536) {
        int u = t - 2048;
        int lane = u & 63;
        int tile = u >> 6;
        int nt = tile % 3, s = tile / 3;
        int g = lane >> 4, col = (lane & 15) + nt * 16;
        unsigned short* p = w2f + (size_t)u * 8;
        #pragma unroll
        for (int e = 0; e < 8; ++e) {
            int k = 32 * s + 8 * g + e;
            p[e] = (col < NC) ? (unsigned short)bf16r(W2[k * NC + col]) : 0;
        }
    }
}

// ---------------- init: y = 0.5*x (f32) ; g = bf16(dinv * 0.5*x) ----------------

static __global__ __launch_bounds__(256) void k_init(const float4* __restrict__ x4,
                                                     float4* __restrict__ y4,
                                                     uint4* __restrict__ gb,
                                                     const float2* __restrict__ drd,
                                                     int nchunk)
{
    int i = blockIdx.x * 256 + threadIdx.x;
    if (i >= nchunk) return;
    float d1 = drd[i >> 3].x;
    float4 a = x4[i * 2], b = x4[i * 2 + 1];
    a.x *= 0.5f; a.y *= 0.5f; a.z *= 0.5f; a.w *= 0.5f;
    b.x *= 0.5f; b.y *= 0.5f; b.z *= 0.5f; b.w *= 0.5f;
    y4[i * 2] = a; y4[i * 2 + 1] = b;
    gb[i] = make_uint4(packbf(a.x * d1, a.y * d1), packbf(a.z * d1, a.w * d1),
                       packbf(b.x * d1, b.y * d1), packbf(b.z * d1, b.w * d1));
}

// ---------------- SpMM on g = dinv*h: half-wave per row, lane = u32 ----------------
// S = sum_e g[col_e] + g[row]; h_next = dinv*S; g_next = dinv*h_next.
// ACC iterations fold y += h_k (= g_k[row]*rd) + h_{k+1}.

template<bool ACC>
static __global__ __launch_bounds__(256) void k_spmm(const unsigned* __restrict__ gb,
                                                     unsigned* __restrict__ go,
                                                     float2* __restrict__ y2,
                                                     const int* __restrict__ rp,
                                                     const int* __restrict__ ccol,
                                                     const float2* __restrict__ drd, int n)
{
    int wid  = (blockIdx.x * 256 + threadIdx.x) >> 6;
    int lane = threadIdx.x & 63;
    int row  = wid * 2 + (lane >> 5);
    int j    = lane & 31;            // u32 slot within the 128B bf16 row
    if (row >= n) return;
    int s = rp[row], e = rp[row + 1];

    float aL0 = 0.f, aR0 = 0.f, aL1 = 0.f, aR1 = 0.f;
    int i = s;
    for (; i + 3 < e; i += 4) {
        int c0 = ccol[i], c1 = ccol[i + 1], c2 = ccol[i + 2], c3 = ccol[i + 3];
        unsigned h0 = gb[(size_t)c0 * 32 + j];
        unsigned h1 = gb[(size_t)c1 * 32 + j];
        unsigned h2 = gb[(size_t)c2 * 32 + j];
        unsigned h3 = gb[(size_t)c3 * 32 + j];
        aL0 += bflo(h0); aR0 += bfhi(h0);
        aL1 += bflo(h1); aR1 += bfhi(h1);
        aL0 += bflo(h2); aR0 += bfhi(h2);
        aL1 += bflo(h3); aR1 += bfhi(h3);
    }
    for (; i < e; ++i) {
        unsigned h = gb[(size_t)ccol[i] * 32 + j];
        aL0 += bflo(h); aR0 += bfhi(h);
    }

    float2 dr = drd[row];
    unsigned gs = gb[(size_t)row * 32 + j];
    float gsL = bflo(gs), gsR = bfhi(gs);
    float SL = (aL0 + aL1) + gsL;
    float SR = (aR0 + aR1) + gsR;
    float hL = dr.x * SL, hR = dr.x * SR;          // h_{k+1}
    go[(size_t)row * 32 + j] = packbf(dr.x * hL, dr.x * hR);  // g_{k+1}
    if (ACC) {
        float2 yv = y2[(size_t)row * 32 + j];
        yv.x += fmaf(gsL, dr.y, hL);               // h_k + h_{k+1}
        yv.y += fmaf(gsR, dr.y, hR);
        y2[(size_t)row * 32 + j] = yv;
    }
}

// ---------------- MFMA MLP: 64 rows/block, 4 waves (unchanged) ----------------

#define YSTR 72    // shorts per ys row
#define HSTR 264   // shorts per hs row

static __global__ __launch_bounds__(256) void k_mlp(const float4* __restrict__ y4,
                                                    const short8* __restrict__ w1f,
                                                    const short8* __restrict__ w2f,
                                                    const float* __restrict__ b1,
                                                    const float* __restrict__ b2,
                                                    float* __restrict__ out, int n)
{
    __shared__ short lds[64 * HSTR];   // 33.8 KB; first 64*YSTR shorts = ys
    int t = threadIdx.x;
    int lane = t & 63;
    int w = t >> 6;
    int base = blockIdx.x * 64;
    const float S = 1.f / 9.f;

    {
        int r = t >> 2, q = t & 3;
        int row = base + r;
        unsigned v[8];
        if (row < n) {
            const float4* yp = y4 + (size_t)row * 16 + q * 4;
            #pragma unroll
            for (int i = 0; i < 4; ++i) {
                float4 f = yp[i];
                v[i * 2]     = packbf(f.x * S, f.y * S);
                v[i * 2 + 1] = packbf(f.z * S, f.w * S);
            }
        } else {
            #pragma unroll
            for (int i = 0; i < 8; ++i) v[i] = 0;
        }
        uint4* dst = (uint4*)&lds[r * YSTR + q * 16];
        dst[0] = make_uint4(v[0], v[1], v[2], v[3]);
        dst[1] = make_uint4(v[4], v[5], v[6], v[7]);
    }
    __syncthreads();

    int m = lane & 15, g = lane >> 4;

    f32x4 acc[4][4];
    {
        short8 a[4][2];
        #pragma unroll
        for (int mt = 0; mt < 4; ++mt)
            #pragma unroll
            for (int s = 0; s < 2; ++s)
                a[mt][s] = *(const short8*)&lds[(mt * 16 + m) * YSTR + s * 32 + g * 8];
        #pragma unroll
        for (int nt4 = 0; nt4 < 4; ++nt4) {
            int nt = w * 4 + nt4;
            short8 b0  = w1f[nt * 64 + lane];
            short8 b1v = w1f[(16 + nt) * 64 + lane];
            float bias = b1[nt * 16 + m];
            #pragma unroll
            for (int mt = 0; mt < 4; ++mt) {
                f32x4 c = {bias, bias, bias, bias};
                c = __builtin_amdgcn_mfma_f32_16x16x32_bf16(a[mt][0], b0,  c, 0, 0, 0);
                c = __builtin_amdgcn_mfma_f32_16x16x32_bf16(a[mt][1], b1v, c, 0, 0, 0);
                acc[mt][nt4] = c;
            }
        }
    }
    __syncthreads();

    {
        #pragma unroll
        for (int mt = 0; mt < 4; ++mt)
            #pragma unroll
            for (int nt4 = 0; nt4 < 4; ++nt4) {
                int col = w * 64 + nt4 * 16 + m;
                #pragma unroll
                for (int r = 0; r < 4; ++r) {
                    float hv = fmaxf(acc[mt][nt4][r], 0.f);
                    lds[(mt * 16 + g * 4 + r) * HSTR + col] = (short)bf16r(hv);
                }
            }
    }
    __syncthreads();

    {
        short8 a2[8];
        #pragma unroll
        for (int s = 0; s < 8; ++s)
            a2[s] = *(const short8*)&lds[(w * 16 + m) * HSTR + s * 32 + g * 8];
        #pragma unroll
        for (int nt = 0; nt < 3; ++nt) {
            int col = nt * 16 + m;
            float bias = (col < NC) ? b2[col] : 0.f;
            f32x4 c = {bias, bias, bias, bias};
            #pragma unroll
            for (int s = 0; s < 8; ++s)
                c = __builtin_amdgcn_mfma_f32_16x16x32_bf16(a2[s], w2f[(s * 3 + nt) * 64 + lane], c, 0, 0, 0);
            if (col < NC) {
                #pragma unroll
                for (int r = 0; r < 4; ++r) {
                    int row = base + w * 16 + g * 4 + r;
                    if (row < n) out[(size_t)row * NC + col] = c[r];
                }
            }
        }
    }
}

// ---------------- launch ----------------

extern "C" void kernel_launch(void* const* d_in, const int* in_sizes, int n_in,
                              void* d_out, int out_size, void* d_ws, size_t ws_size,
                              hipStream_t stream)
{
    const float* x  = (const float*)d_in[0];
    const int*   ei = (const int*)d_in[1];
    const float* W1 = (const float*)d_in[2];
    const float* b1 = (const float*)d_in[3];
    const float* W2 = (const float*)d_in[4];
    const float* b2 = (const float*)d_in[5];
    float* out = (float*)d_out;

    const int n = NN, E = NE;
    const int nb = (n + SC - 1) / SC;  // 98 scan blocks

    char* ws = (char*)d_ws;
    size_t off = 0;
    auto alloc = [&](size_t bytes) -> void* {
        void* p = ws + off;
        off = (off + bytes + 255) & ~(size_t)255;
        return p;
    };
    int*    cnt  = (int*)   alloc((size_t)n * 4);
    int*    fill = (int*)   alloc((size_t)n * 4);
    int*    rp   = (int*)   alloc((size_t)(n + 1) * 4);
    float2* drd  = (float2*)alloc((size_t)n * 8);
    int*    bsum = (int*)   alloc(128 * 4);
    int*    boff = (int*)   alloc(128 * 4);
    int*    ccol = (int*)   alloc((size_t)E * 4);
    unsigned short* w1f = (unsigned short*)alloc(2048 * 8 * 2);
    unsigned short* w2f = (unsigned short*)alloc(1536 * 8 * 2);
    uint4* ha   = (uint4*)alloc((size_t)n * NF * 2);   // bf16 g ping
    uint4* hbuf = (uint4*)alloc((size_t)n * NF * 2);   // bf16 g pong
    float* y    = (float*)alloc((size_t)n * NF * 4);   // f32 accumulator

    hipMemsetAsync(cnt, 0, (size_t)n * 4, stream);
    hipMemsetAsync(fill, 0, (size_t)n * 4, stream);

    const int* rows = ei;
    const int* cols = ei + E;

    k_count  <<<(E + 255) / 256, 256, 0, stream>>>(rows, cnt, E);
    k_bsum   <<<nb, 256, 0, stream>>>(cnt, bsum, n);
    k_scanb  <<<1, 128, 0, stream>>>(bsum, boff, rp, nb, n);
    k_scan3  <<<nb, 256, 0, stream>>>(cnt, boff, rp, drd, n);
    k_scatter<<<512, 256, 0, stream>>>(rows, cols, rp, fill, ccol, E);
    k_pack   <<<14, 256, 0, stream>>>(W1, W2, w1f, w2f);

    int nchunk = n * 8;
    k_init<<<(nchunk + 255) / 256, 256, 0, stream>>>((const float4*)x, (float4*)y,
                                                     ha, drd, nchunk);

    uint4* cur = ha;
    uint4* nxt = hbuf;
    int spmm_blocks = ((size_t)n * 32 + 255) / 256;   // 12500
    for (int it = 0; it < ORDER_C; ++it) {
        if (it & 1)
            k_spmm<true><<<spmm_blocks, 256, 0, stream>>>((const unsigned*)cur, (unsigned*)nxt,
                                                          (float2*)y, rp, ccol, drd, n);
        else
            k_spmm<false><<<spmm_blocks, 256, 0, stream>>>((const unsigned*)cur, (unsigned*)nxt,
                                                           (float2*)y, rp, ccol, drd, n);
        uint4* tswap = cur; cur = nxt; nxt = tswap;
    }

    k_mlp<<<(n + 63) / 64, 256, 0, stream>>>((const float4*)y, (const short8*)w1f,
                                             (const short8*)w2f, b1, b2, out, n);
}

// Round 9
// 410.398 us; speedup vs baseline: 1.4320x; 1.1357x over previous
//
#include <hip/hip_runtime.h>

#define NN 100000
#define NE 1200000
#define NF 64
#define NH 256
#define NC 40
#define ORDER_C 8
#define SC 1024  // scan chunk (elements per block)

typedef __attribute__((ext_vector_type(8))) short short8;
typedef __attribute__((ext_vector_type(4))) float f32x4;

// ---- bf16 helpers (RTNE pack, cheap unpack) ----
__device__ __forceinline__ unsigned bf16r(float x) {
    unsigned u = __float_as_uint(x);
    return (u + 0x7FFFu + ((u >> 16) & 1u)) >> 16;
}
__device__ __forceinline__ unsigned packbf(float lo, float hi) {
    return bf16r(lo) | (bf16r(hi) << 16);
}
__device__ __forceinline__ float bflo(unsigned u) { return __uint_as_float(u << 16); }
__device__ __forceinline__ float bfhi(unsigned u) { return __uint_as_float(u & 0xFFFF0000u); }

// ---------------- CSR build ----------------

static __global__ __launch_bounds__(256) void k_count(const int* __restrict__ rows,
                                                      int* __restrict__ cnt, int E)
{
    int i = blockIdx.x * 256 + threadIdx.x;
    if (i < E) atomicAdd(&cnt[rows[i]], 1);
}

static __global__ __launch_bounds__(256) void k_bsum(const int* __restrict__ cnt,
                                                     int* __restrict__ bsum, int n)
{
    __shared__ int red[256];
    int t = threadIdx.x;
    int idx = blockIdx.x * SC + t * 4;
    int s = 0;
    if (idx + 3 < n) {
        int4 q = *(const int4*)&cnt[idx];
        s = q.x + q.y + q.z + q.w;
    } else {
        for (int j = 0; j < 4; ++j) if (idx + j < n) s += cnt[idx + j];
    }
    red[t] = s;
    __syncthreads();
    for (int off = 128; off > 0; off >>= 1) {
        if (t < off) red[t] += red[t + off];
        __syncthreads();
    }
    if (t == 0) bsum[blockIdx.x] = red[0];
}

static __global__ __launch_bounds__(128) void k_scanb(const int* __restrict__ bsum,
                                                      int* __restrict__ boff,
                                                      int* __restrict__ rp, int nb, int n)
{
    __shared__ int red[128];
    int t = threadIdx.x;
    int v = (t < nb) ? bsum[t] : 0;
    red[t] = v;
    __syncthreads();
    for (int off = 1; off < 128; off <<= 1) {
        int x = (t >= off) ? red[t - off] : 0;
        __syncthreads();
        red[t] += x;
        __syncthreads();
    }
    if (t < nb) boff[t] = (t == 0) ? 0 : red[t - 1];
    if (t == 0) rp[n] = red[127];
}

// scan phase 3: rp + packed (dinv, rd) per row
static __global__ __launch_bounds__(256) void k_scan3(const int* __restrict__ cnt,
                                                      const int* __restrict__ boff,
                                                      int* __restrict__ rp,
                                                      float2* __restrict__ drd, int n)
{
    __shared__ int red[256];
    int t = threadIdx.x;
    int idx = blockIdx.x * SC + t * 4;
    int v[4] = {0, 0, 0, 0};
    if (idx + 3 < n) {
        int4 q = *(const int4*)&cnt[idx];
        v[0] = q.x; v[1] = q.y; v[2] = q.z; v[3] = q.w;
    } else {
        for (int j = 0; j < 4; ++j) if (idx + j < n) v[j] = cnt[idx + j];
    }
    red[t] = v[0] + v[1] + v[2] + v[3];
    __syncthreads();
    for (int off = 1; off < 256; off <<= 1) {
        int x = (t >= off) ? red[t - off] : 0;
        __syncthreads();
        red[t] += x;
        __syncthreads();
    }
    int run = ((t == 0) ? 0 : red[t - 1]) + boff[blockIdx.x];
    #pragma unroll
    for (int j = 0; j < 4; ++j) {
        if (idx + j < n) {
            rp[idx + j] = run;
            float d1 = rsqrtf((float)(v[j] + 1));          // 1/sqrt(deg)
            drd[idx + j] = make_float2(d1, (float)(v[j] + 1) * d1);  // (dinv, sqrt(deg))
            run += v[j];
        }
    }
}

// XCD-partitioned scatter at full occupancy: group g = blockIdx&7 owns rows
// [g*NN/8,(g+1)*NN/8). fillpos starts as a copy of rp, so the atomic returns
// the CSR position directly (no dependent rp read).
static __global__ __launch_bounds__(256) void k_scatter(const int* __restrict__ rows,
                                                        const int* __restrict__ cols,
                                                        int* __restrict__ fillpos,
                                                        int* __restrict__ ccol, int E)
{
    int grp = blockIdx.x & 7;
    int lo = grp * (NN / 8), hi = lo + (NN / 8);
    int stride = (gridDim.x >> 3) * 256;
    for (int i = (blockIdx.x >> 3) * 256 + threadIdx.x; i < E; i += stride) {
        int r = rows[i];
        if (r >= lo && r < hi) {
            int pos = atomicAdd(&fillpos[r], 1);
            ccol[pos] = cols[i];
        }
    }
}

// ---------------- pack W1/W2 into MFMA B-fragment order (bf16) ----------------

static __global__ __launch_bounds__(256) void k_pack(const float* __restrict__ W1,
                                                     const float* __restrict__ W2,
                                                     unsigned short* __restrict__ w1f,
                                                     unsigned short* __restrict__ w2f)
{
    int t = blockIdx.x * 256 + threadIdx.x;
    if (t < 2048) {
        int lane = t & 63;
        int g = lane >> 4, col = (lane & 15) + ((t >> 6) & 15) * 16;
        int s = t >> 10;
        unsigned short* p = w1f + (size_t)t * 8;
        #pragma unroll
        for (int e = 0; e < 8; ++e) {
            int k = 32 * s + 8 * g + e;
            p[e] = (unsigned short)bf16r(W1[k * NH + col]);
        }
    } else if (t < 2048 + 1536) {
        int u = t - 2048;
        int lane = u & 63;
        int tile = u >> 6;
        int nt = tile % 3, s = tile / 3;
        int g = lane >> 4, col = (lane & 15) + nt * 16;
        unsigned short* p = w2f + (size_t)u * 8;
        #pragma unroll
        for (int e = 0; e < 8; ++e) {
            int k = 32 * s + 8 * g + e;
            p[e] = (col < NC) ? (unsigned short)bf16r(W2[k * NC + col]) : 0;
        }
    }
}

// ---------------- init: y = 0.5*x (f32) ; g = bf16(dinv * 0.5*x) ----------------

static __global__ __launch_bounds__(256) void k_init(const float4* __restrict__ x4,
                                                     float4* __restrict__ y4,
                                                     uint4* __restrict__ gb,
                                                     const float2* __restrict__ drd,
                                                     int nchunk)
{
    int i = blockIdx.x * 256 + threadIdx.x;
    if (i >= nchunk) return;
    float d1 = drd[i >> 3].x;
    float4 a = x4[i * 2], b = x4[i * 2 + 1];
    a.x *= 0.5f; a.y *= 0.5f; a.z *= 0.5f; a.w *= 0.5f;
    b.x *= 0.5f; b.y *= 0.5f; b.z *= 0.5f; b.w *= 0.5f;
    y4[i * 2] = a; y4[i * 2 + 1] = b;
    gb[i] = make_uint4(packbf(a.x * d1, a.y * d1), packbf(a.z * d1, a.w * d1),
                       packbf(b.x * d1, b.y * d1), packbf(b.z * d1, b.w * d1));
}

// ---------------- SpMM on g = dinv*h: 4 rows/wave, 16 lanes x uint2 per row ----------------
// S = sum_e g[col_e] + g[row]; h_next = dinv*S; g_next = dinv*h_next.
// ACC iterations fold y += h_k (= g_k[row]*rd) + h_{k+1}.

template<bool ACC>
static __global__ __launch_bounds__(256) void k_spmm(const uint2* __restrict__ gb,
                                                     uint2* __restrict__ go,
                                                     float4* __restrict__ y4,
                                                     const int* __restrict__ rp,
                                                     const int* __restrict__ ccol,
                                                     const float2* __restrict__ drd, int n)
{
    int wid  = (blockIdx.x * 256 + threadIdx.x) >> 6;
    int lane = threadIdx.x & 63;
    int row  = wid * 4 + (lane >> 4);
    int j    = lane & 15;            // uint2 slot (4 bf16 feats) within 128B row
    if (row >= n) return;
    int s = rp[row], e = rp[row + 1];

    float a0 = 0.f, a1 = 0.f, a2 = 0.f, a3 = 0.f;   // chain A
    float b0 = 0.f, b1 = 0.f, b2 = 0.f, b3 = 0.f;   // chain B
    int i = s;
    for (; i + 3 < e; i += 4) {
        int c0 = ccol[i], c1 = ccol[i + 1], c2 = ccol[i + 2], c3 = ccol[i + 3];
        uint2 h0 = gb[(size_t)c0 * 16 + j];
        uint2 h1 = gb[(size_t)c1 * 16 + j];
        uint2 h2 = gb[(size_t)c2 * 16 + j];
        uint2 h3 = gb[(size_t)c3 * 16 + j];
        a0 += bflo(h0.x); a1 += bfhi(h0.x); a2 += bflo(h0.y); a3 += bfhi(h0.y);
        b0 += bflo(h1.x); b1 += bfhi(h1.x); b2 += bflo(h1.y); b3 += bfhi(h1.y);
        a0 += bflo(h2.x); a1 += bfhi(h2.x); a2 += bflo(h2.y); a3 += bfhi(h2.y);
        b0 += bflo(h3.x); b1 += bfhi(h3.x); b2 += bflo(h3.y); b3 += bfhi(h3.y);
    }
    for (; i < e; ++i) {
        uint2 h = gb[(size_t)ccol[i] * 16 + j];
        a0 += bflo(h.x); a1 += bfhi(h.x); a2 += bflo(h.y); a3 += bfhi(h.y);
    }

    float2 dr = drd[row];
    uint2 gs = gb[(size_t)row * 16 + j];
    float g0 = bflo(gs.x), g1 = bfhi(gs.x), g2 = bflo(gs.y), g3 = bfhi(gs.y);
    float s0 = (a0 + b0) + g0;
    float s1 = (a1 + b1) + g1;
    float s2 = (a2 + b2) + g2;
    float s3 = (a3 + b3) + g3;
    float h0 = dr.x * s0, h1 = dr.x * s1, h2 = dr.x * s2, h3 = dr.x * s3;  // h_{k+1}
    go[(size_t)row * 16 + j] = make_uint2(packbf(dr.x * h0, dr.x * h1),
                                          packbf(dr.x * h2, dr.x * h3));  // g_{k+1}
    if (ACC) {
        float4 yv = y4[(size_t)row * 16 + j];
        yv.x += fmaf(g0, dr.y, h0);               // h_k + h_{k+1}
        yv.y += fmaf(g1, dr.y, h1);
        yv.z += fmaf(g2, dr.y, h2);
        yv.w += fmaf(g3, dr.y, h3);
        y4[(size_t)row * 16 + j] = yv;
    }
}

// ---------------- MFMA MLP: 64 rows/block, 4 waves (unchanged) ----------------

#define YSTR 72    // shorts per ys row
#define HSTR 264   // shorts per hs row

static __global__ __launch_bounds__(256) void k_mlp(const float4* __restrict__ y4,
                                                    const short8* __restrict__ w1f,
                                                    const short8* __restrict__ w2f,
                                                    const float* __restrict__ b1,
                                                    const float* __restrict__ b2,
                                                    float* __restrict__ out, int n)
{
    __shared__ short lds[64 * HSTR];   // 33.8 KB; first 64*YSTR shorts = ys
    int t = threadIdx.x;
    int lane = t & 63;
    int w = t >> 6;
    int base = blockIdx.x * 64;
    const float S = 1.f / 9.f;

    {
        int r = t >> 2, q = t & 3;
        int row = base + r;
        unsigned v[8];
        if (row < n) {
            const float4* yp = y4 + (size_t)row * 16 + q * 4;
            #pragma unroll
            for (int i = 0; i < 4; ++i) {
                float4 f = yp[i];
                v[i * 2]     = packbf(f.x * S, f.y * S);
                v[i * 2 + 1] = packbf(f.z * S, f.w * S);
            }
        } else {
            #pragma unroll
            for (int i = 0; i < 8; ++i) v[i] = 0;
        }
        uint4* dst = (uint4*)&lds[r * YSTR + q * 16];
        dst[0] = make_uint4(v[0], v[1], v[2], v[3]);
        dst[1] = make_uint4(v[4], v[5], v[6], v[7]);
    }
    __syncthreads();

    int m = lane & 15, g = lane >> 4;

    f32x4 acc[4][4];
    {
        short8 a[4][2];
        #pragma unroll
        for (int mt = 0; mt < 4; ++mt)
            #pragma unroll
            for (int s = 0; s < 2; ++s)
                a[mt][s] = *(const short8*)&lds[(mt * 16 + m) * YSTR + s * 32 + g * 8];
        #pragma unroll
        for (int nt4 = 0; nt4 < 4; ++nt4) {
            int nt = w * 4 + nt4;
            short8 b0  = w1f[nt * 64 + lane];
            short8 b1v = w1f[(16 + nt) * 64 + lane];
            float bias = b1[nt * 16 + m];
            #pragma unroll
            for (int mt = 0; mt < 4; ++mt) {
                f32x4 c = {bias, bias, bias, bias};
                c = __builtin_amdgcn_mfma_f32_16x16x32_bf16(a[mt][0], b0,  c, 0, 0, 0);
                c = __builtin_amdgcn_mfma_f32_16x16x32_bf16(a[mt][1], b1v, c, 0, 0, 0);
                acc[mt][nt4] = c;
            }
        }
    }
    __syncthreads();

    {
        #pragma unroll
        for (int mt = 0; mt < 4; ++mt)
            #pragma unroll
            for (int nt4 = 0; nt4 < 4; ++nt4) {
                int col = w * 64 + nt4 * 16 + m;
                #pragma unroll
                for (int r = 0; r < 4; ++r) {
                    float hv = fmaxf(acc[mt][nt4][r], 0.f);
                    lds[(mt * 16 + g * 4 + r) * HSTR + col] = (short)bf16r(hv);
                }
            }
    }
    __syncthreads();

    {
        short8 a2[8];
        #pragma unroll
        for (int s = 0; s < 8; ++s)
            a2[s] = *(const short8*)&lds[(w * 16 + m) * HSTR + s * 32 + g * 8];
        #pragma unroll
        for (int nt = 0; nt < 3; ++nt) {
            int col = nt * 16 + m;
            float bias = (col < NC) ? b2[col] : 0.f;
            f32x4 c = {bias, bias, bias, bias};
            #pragma unroll
            for (int s = 0; s < 8; ++s)
                c = __builtin_amdgcn_mfma_f32_16x16x32_bf16(a2[s], w2f[(s * 3 + nt) * 64 + lane], c, 0, 0, 0);
            if (col < NC) {
                #pragma unroll
                for (int r = 0; r < 4; ++r) {
                    int row = base + w * 16 + g * 4 + r;
                    if (row < n) out[(size_t)row * NC + col] = c[r];
                }
            }
        }
    }
}

// ---------------- launch ----------------

extern "C" void kernel_launch(void* const* d_in, const int* in_sizes, int n_in,
                              void* d_out, int out_size, void* d_ws, size_t ws_size,
                              hipStream_t stream)
{
    const float* x  = (const float*)d_in[0];
    const int*   ei = (const int*)d_in[1];
    const float* W1 = (const float*)d_in[2];
    const float* b1 = (const float*)d_in[3];
    const float* W2 = (const float*)d_in[4];
    const float* b2 = (const float*)d_in[5];
    float* out = (float*)d_out;

    const int n = NN, E = NE;
    const int nb = (n + SC - 1) / SC;  // 98 scan blocks

    char* ws = (char*)d_ws;
    size_t off = 0;
    auto alloc = [&](size_t bytes) -> void* {
        void* p = ws + off;
        off = (off + bytes + 255) & ~(size_t)255;
        return p;
    };
    int*    cnt  = (int*)   alloc((size_t)n * 4);
    int*    fill = (int*)   alloc((size_t)n * 4);
    int*    rp   = (int*)   alloc((size_t)(n + 1) * 4);
    float2* drd  = (float2*)alloc((size_t)n * 8);
    int*    bsum = (int*)   alloc(128 * 4);
    int*    boff = (int*)   alloc(128 * 4);
    int*    ccol = (int*)   alloc((size_t)E * 4);
    unsigned short* w1f = (unsigned short*)alloc(2048 * 8 * 2);
    unsigned short* w2f = (unsigned short*)alloc(1536 * 8 * 2);
    uint4* ha   = (uint4*)alloc((size_t)n * NF * 2);   // bf16 g ping
    uint4* hbuf = (uint4*)alloc((size_t)n * NF * 2);   // bf16 g pong
    float* y    = (float*)alloc((size_t)n * NF * 4);   // f32 accumulator

    hipMemsetAsync(cnt, 0, (size_t)n * 4, stream);

    const int* rows = ei;
    const int* cols = ei + E;

    k_count  <<<(E + 255) / 256, 256, 0, stream>>>(rows, cnt, E);
    k_bsum   <<<nb, 256, 0, stream>>>(cnt, bsum, n);
    k_scanb  <<<1, 128, 0, stream>>>(bsum, boff, rp, nb, n);
    k_scan3  <<<nb, 256, 0, stream>>>(cnt, boff, rp, drd, n);
    hipMemcpyAsync(fill, rp, (size_t)n * 4, hipMemcpyDeviceToDevice, stream);
    k_scatter<<<4096, 256, 0, stream>>>(rows, cols, fill, ccol, E);
    k_pack   <<<14, 256, 0, stream>>>(W1, W2, w1f, w2f);

    int nchunk = n * 8;
    k_init<<<(nchunk + 255) / 256, 256, 0, stream>>>((const float4*)x, (float4*)y,
                                                     ha, drd, nchunk);

    uint4* cur = ha;
    uint4* nxt = hbuf;
    int spmm_blocks = (n + 15) / 16;   // 4 rows/wave, 4 waves/block
    for (int it = 0; it < ORDER_C; ++it) {
        if (it & 1)
            k_spmm<true><<<spmm_blocks, 256, 0, stream>>>((const uint2*)cur, (uint2*)nxt,
                                                          (float4*)y, rp, ccol, drd, n);
        else
            k_spmm<false><<<spmm_blocks, 256, 0, stream>>>((const uint2*)cur, (uint2*)nxt,
                                                           (float4*)y, rp, ccol, drd, n);
        uint4* tswap = cur; cur = nxt; nxt = tswap;
    }

    k_mlp<<<(n + 63) / 64, 256, 0, stream>>>((const float4*)y, (const short8*)w1f,
                                             (const short8*)w2f, b1, b2, out, n);
}

// Round 10
// 403.057 us; speedup vs baseline: 1.4580x; 1.0182x over previous
//
#include <hip/hip_runtime.h>

#define NN 100000
#define NE 1200000
#define NF 64
#define NH 256
#define NC 40
#define ORDER_C 8
#define SC 1024    // scan chunk (elements per block)
#define BINB 2048  // edges per binning block
#define BCAP 165000 // bucket capacity (expected 150K, sigma ~400)

typedef __attribute__((ext_vector_type(8))) short short8;
typedef __attribute__((ext_vector_type(4))) float f32x4;

// ---- bf16 helpers (RTNE pack, cheap unpack) ----
__device__ __forceinline__ unsigned bf16r(float x) {
    unsigned u = __float_as_uint(x);
    return (u + 0x7FFFu + ((u >> 16) & 1u)) >> 16;
}
__device__ __forceinline__ unsigned packbf(float lo, float hi) {
    return bf16r(lo) | (bf16r(hi) << 16);
}
__device__ __forceinline__ float bflo(unsigned u) { return __uint_as_float(u << 16); }
__device__ __forceinline__ float bfhi(unsigned u) { return __uint_as_float(u & 0xFFFF0000u); }

// ---------------- binning pass: degree count + bucket append (reads edges ONCE) ----
// bucket b = r / 12500 (8 row-range buckets). Per-block LDS histogram ->
// one global reservation per bucket -> contiguous pair writes (full lines).

static __global__ __launch_bounds__(256) void k_bin(const int* __restrict__ rows,
                                                    const int* __restrict__ cols,
                                                    int* __restrict__ cnt,
                                                    int* __restrict__ bcnt,
                                                    int2* __restrict__ bbuf, int E)
{
    __shared__ int rbuf[BINB];
    __shared__ unsigned short lofs[BINB];
    __shared__ int hist[8], basew[8];
    int t = threadIdx.x;
    int e0 = blockIdx.x * BINB;
    int m = E - e0; if (m > BINB) m = BINB;
    if (t < 8) hist[t] = 0;
    __syncthreads();
    for (int i = t; i < m; i += 256) {
        int r = rows[e0 + i];
        rbuf[i] = r;
        atomicAdd(&cnt[r], 1);                       // degree count (global, no return use)
        int b = r / 12500;
        lofs[i] = (unsigned short)atomicAdd(&hist[b], 1);
    }
    __syncthreads();
    if (t < 8) basew[t] = atomicAdd(&bcnt[t], hist[t]);
    __syncthreads();
    for (int i = t; i < m; i += 256) {
        int r = rbuf[i];
        int b = r / 12500;
        bbuf[(size_t)b * BCAP + basew[b] + lofs[i]] = make_int2(r, cols[e0 + i]);
    }
}

// ---------------- scan phases (unchanged) ----------------

static __global__ __launch_bounds__(256) void k_bsum(const int* __restrict__ cnt,
                                                     int* __restrict__ bsum, int n)
{
    __shared__ int red[256];
    int t = threadIdx.x;
    int idx = blockIdx.x * SC + t * 4;
    int s = 0;
    if (idx + 3 < n) {
        int4 q = *(const int4*)&cnt[idx];
        s = q.x + q.y + q.z + q.w;
    } else {
        for (int j = 0; j < 4; ++j) if (idx + j < n) s += cnt[idx + j];
    }
    red[t] = s;
    __syncthreads();
    for (int off = 128; off > 0; off >>= 1) {
        if (t < off) red[t] += red[t + off];
        __syncthreads();
    }
    if (t == 0) bsum[blockIdx.x] = red[0];
}

static __global__ __launch_bounds__(128) void k_scanb(const int* __restrict__ bsum,
                                                      int* __restrict__ boff,
                                                      int* __restrict__ rp, int nb, int n)
{
    __shared__ int red[128];
    int t = threadIdx.x;
    int v = (t < nb) ? bsum[t] : 0;
    red[t] = v;
    __syncthreads();
    for (int off = 1; off < 128; off <<= 1) {
        int x = (t >= off) ? red[t - off] : 0;
        __syncthreads();
        red[t] += x;
        __syncthreads();
    }
    if (t < nb) boff[t] = (t == 0) ? 0 : red[t - 1];
    if (t == 0) rp[n] = red[127];
}

static __global__ __launch_bounds__(256) void k_scan3(const int* __restrict__ cnt,
                                                      const int* __restrict__ boff,
                                                      int* __restrict__ rp,
                                                      float2* __restrict__ drd, int n)
{
    __shared__ int red[256];
    int t = threadIdx.x;
    int idx = blockIdx.x * SC + t * 4;
    int v[4] = {0, 0, 0, 0};
    if (idx + 3 < n) {
        int4 q = *(const int4*)&cnt[idx];
        v[0] = q.x; v[1] = q.y; v[2] = q.z; v[3] = q.w;
    } else {
        for (int j = 0; j < 4; ++j) if (idx + j < n) v[j] = cnt[idx + j];
    }
    red[t] = v[0] + v[1] + v[2] + v[3];
    __syncthreads();
    for (int off = 1; off < 256; off <<= 1) {
        int x = (t >= off) ? red[t - off] : 0;
        __syncthreads();
        red[t] += x;
        __syncthreads();
    }
    int run = ((t == 0) ? 0 : red[t - 1]) + boff[blockIdx.x];
    #pragma unroll
    for (int j = 0; j < 4; ++j) {
        if (idx + j < n) {
            rp[idx + j] = run;
            float d1 = rsqrtf((float)(v[j] + 1));          // 1/sqrt(deg)
            drd[idx + j] = make_float2(d1, (float)(v[j] + 1) * d1);  // (dinv, sqrt(deg))
            run += v[j];
        }
    }
}

// ---------------- phase-2 scatter: group g consumes bucket g (L2-resident) ----------------

static __global__ __launch_bounds__(256) void k_scat2(const int2* __restrict__ bbuf,
                                                      const int* __restrict__ bcnt,
                                                      int* __restrict__ fillpos,
                                                      int* __restrict__ ccol)
{
    int grp = blockIdx.x & 7;
    int m = bcnt[grp];
    const int2* src = bbuf + (size_t)grp * BCAP;
    int stride = (gridDim.x >> 3) * 256;
    for (int i = (blockIdx.x >> 3) * 256 + threadIdx.x; i < m; i += stride) {
        int2 rc = src[i];
        int pos = atomicAdd(&fillpos[rc.x], 1);
        ccol[pos] = rc.y;
    }
}

// ---------------- pack W1/W2 into MFMA B-fragment order (bf16) ----------------

static __global__ __launch_bounds__(256) void k_pack(const float* __restrict__ W1,
                                                     const float* __restrict__ W2,
                                                     unsigned short* __restrict__ w1f,
                                                     unsigned short* __restrict__ w2f)
{
    int t = blockIdx.x * 256 + threadIdx.x;
    if (t < 2048) {
        int lane = t & 63;
        int g = lane >> 4, col = (lane & 15) + ((t >> 6) & 15) * 16;
        int s = t >> 10;
        unsigned short* p = w1f + (size_t)t * 8;
        #pragma unroll
        for (int e = 0; e < 8; ++e) {
            int k = 32 * s + 8 * g + e;
            p[e] = (unsigned short)bf16r(W1[k * NH + col]);
        }
    } else if (t < 2048 + 1536) {
        int u = t - 2048;
        int lane = u & 63;
        int tile = u >> 6;
        int nt = tile % 3, s = tile / 3;
        int g = lane >> 4, col = (lane & 15) + nt * 16;
        unsigned short* p = w2f + (size_t)u * 8;
        #pragma unroll
        for (int e = 0; e < 8; ++e) {
            int k = 32 * s + 8 * g + e;
            p[e] = (col < NC) ? (unsigned short)bf16r(W2[k * NC + col]) : 0;
        }
    }
}

// ---------------- init: y = 0.5*x (f32) ; g = bf16(dinv * 0.5*x) ----------------

static __global__ __launch_bounds__(256) void k_init(const float4* __restrict__ x4,
                                                     float4* __restrict__ y4,
                                                     uint4* __restrict__ gb,
                                                     const float2* __restrict__ drd,
                                                     int nchunk)
{
    int i = blockIdx.x * 256 + threadIdx.x;
    if (i >= nchunk) return;
    float d1 = drd[i >> 3].x;
    float4 a = x4[i * 2], b = x4[i * 2 + 1];
    a.x *= 0.5f; a.y *= 0.5f; a.z *= 0.5f; a.w *= 0.5f;
    b.x *= 0.5f; b.y *= 0.5f; b.z *= 0.5f; b.w *= 0.5f;
    y4[i * 2] = a; y4[i * 2 + 1] = b;
    gb[i] = make_uint4(packbf(a.x * d1, a.y * d1), packbf(a.z * d1, a.w * d1),
                       packbf(b.x * d1, b.y * d1), packbf(b.z * d1, b.w * d1));
}

// ---------------- SpMM on g = dinv*h: 4 rows/wave, unroll 8 (16 lanes x uint2) ----------------
// S = sum_e g[col_e] + g[row]; h_next = dinv*S; g_next = dinv*h_next.
// ACC iterations fold y += h_k (= g_k[row]*rd) + h_{k+1}.

template<bool ACC>
static __global__ __launch_bounds__(256) void k_spmm(const uint2* __restrict__ gb,
                                                     uint2* __restrict__ go,
                                                     float4* __restrict__ y4,
                                                     const int* __restrict__ rp,
                                                     const int* __restrict__ ccol,
                                                     const float2* __restrict__ drd, int n)
{
    int wid  = (blockIdx.x * 256 + threadIdx.x) >> 6;
    int lane = threadIdx.x & 63;
    int row  = wid * 4 + (lane >> 4);
    int j    = lane & 15;            // uint2 slot (4 bf16 feats) within 128B row
    if (row >= n) return;
    int s = rp[row], e = rp[row + 1];

    float a0 = 0.f, a1 = 0.f, a2 = 0.f, a3 = 0.f;   // chain A
    float b0 = 0.f, b1 = 0.f, b2 = 0.f, b3 = 0.f;   // chain B
    int i = s;
    for (; i + 7 < e; i += 8) {
        int c0 = ccol[i],     c1 = ccol[i + 1], c2 = ccol[i + 2], c3 = ccol[i + 3];
        int c4 = ccol[i + 4], c5 = ccol[i + 5], c6 = ccol[i + 6], c7 = ccol[i + 7];
        uint2 h0 = gb[(size_t)c0 * 16 + j];
        uint2 h1 = gb[(size_t)c1 * 16 + j];
        uint2 h2 = gb[(size_t)c2 * 16 + j];
        uint2 h3 = gb[(size_t)c3 * 16 + j];
        uint2 h4 = gb[(size_t)c4 * 16 + j];
        uint2 h5 = gb[(size_t)c5 * 16 + j];
        uint2 h6 = gb[(size_t)c6 * 16 + j];
        uint2 h7 = gb[(size_t)c7 * 16 + j];
        a0 += bflo(h0.x); a1 += bfhi(h0.x); a2 += bflo(h0.y); a3 += bfhi(h0.y);
        b0 += bflo(h1.x); b1 += bfhi(h1.x); b2 += bflo(h1.y); b3 += bfhi(h1.y);
        a0 += bflo(h2.x); a1 += bfhi(h2.x); a2 += bflo(h2.y); a3 += bfhi(h2.y);
        b0 += bflo(h3.x); b1 += bfhi(h3.x); b2 += bflo(h3.y); b3 += bfhi(h3.y);
        a0 += bflo(h4.x); a1 += bfhi(h4.x); a2 += bflo(h4.y); a3 += bfhi(h4.y);
        b0 += bflo(h5.x); b1 += bfhi(h5.x); b2 += bflo(h5.y); b3 += bfhi(h5.y);
        a0 += bflo(h6.x); a1 += bfhi(h6.x); a2 += bflo(h6.y); a3 += bfhi(h6.y);
        b0 += bflo(h7.x); b1 += bfhi(h7.x); b2 += bflo(h7.y); b3 += bfhi(h7.y);
    }
    for (; i + 3 < e; i += 4) {
        int c0 = ccol[i], c1 = ccol[i + 1], c2 = ccol[i + 2], c3 = ccol[i + 3];
        uint2 h0 = gb[(size_t)c0 * 16 + j];
        uint2 h1 = gb[(size_t)c1 * 16 + j];
        uint2 h2 = gb[(size_t)c2 * 16 + j];
        uint2 h3 = gb[(size_t)c3 * 16 + j];
        a0 += bflo(h0.x); a1 += bfhi(h0.x); a2 += bflo(h0.y); a3 += bfhi(h0.y);
        b0 += bflo(h1.x); b1 += bfhi(h1.x); b2 += bflo(h1.y); b3 += bfhi(h1.y);
        a0 += bflo(h2.x); a1 += bfhi(h2.x); a2 += bflo(h2.y); a3 += bfhi(h2.y);
        b0 += bflo(h3.x); b1 += bfhi(h3.x); b2 += bflo(h3.y); b3 += bfhi(h3.y);
    }
    for (; i < e; ++i) {
        uint2 h = gb[(size_t)ccol[i] * 16 + j];
        a0 += bflo(h.x); a1 += bfhi(h.x); a2 += bflo(h.y); a3 += bfhi(h.y);
    }

    float2 dr = drd[row];
    uint2 gs = gb[(size_t)row * 16 + j];
    float g0 = bflo(gs.x), g1 = bfhi(gs.x), g2 = bflo(gs.y), g3 = bfhi(gs.y);
    float s0 = (a0 + b0) + g0;
    float s1 = (a1 + b1) + g1;
    float s2 = (a2 + b2) + g2;
    float s3 = (a3 + b3) + g3;
    float h0 = dr.x * s0, h1 = dr.x * s1, h2 = dr.x * s2, h3 = dr.x * s3;  // h_{k+1}
    go[(size_t)row * 16 + j] = make_uint2(packbf(dr.x * h0, dr.x * h1),
                                          packbf(dr.x * h2, dr.x * h3));  // g_{k+1}
    if (ACC) {
        float4 yv = y4[(size_t)row * 16 + j];
        yv.x += fmaf(g0, dr.y, h0);               // h_k + h_{k+1}
        yv.y += fmaf(g1, dr.y, h1);
        yv.z += fmaf(g2, dr.y, h2);
        yv.w += fmaf(g3, dr.y, h3);
        y4[(size_t)row * 16 + j] = yv;
    }
}

// ---------------- MFMA MLP: 64 rows/block, 4 waves (unchanged) ----------------

#define YSTR 72    // shorts per ys row
#define HSTR 264   // shorts per hs row

static __global__ __launch_bounds__(256) void k_mlp(const float4* __restrict__ y4,
                                                    const short8* __restrict__ w1f,
                                                    const short8* __restrict__ w2f,
                                                    const float* __restrict__ b1,
                                                    const float* __restrict__ b2,
                                                    float* __restrict__ out, int n)
{
    __shared__ short lds[64 * HSTR];   // 33.8 KB; first 64*YSTR shorts = ys
    int t = threadIdx.x;
    int lane = t & 63;
    int w = t >> 6;
    int base = blockIdx.x * 64;
    const float S = 1.f / 9.f;

    {
        int r = t >> 2, q = t & 3;
        int row = base + r;
        unsigned v[8];
        if (row < n) {
            const float4* yp = y4 + (size_t)row * 16 + q * 4;
            #pragma unroll
            for (int i = 0; i < 4; ++i) {
                float4 f = yp[i];
                v[i * 2]     = packbf(f.x * S, f.y * S);
                v[i * 2 + 1] = packbf(f.z * S, f.w * S);
            }
        } else {
            #pragma unroll
            for (int i = 0; i < 8; ++i) v[i] = 0;
        }
        uint4* dst = (uint4*)&lds[r * YSTR + q * 16];
        dst[0] = make_uint4(v[0], v[1], v[2], v[3]);
        dst[1] = make_uint4(v[4], v[5], v[6], v[7]);
    }
    __syncthreads();

    int m = lane & 15, g = lane >> 4;

    f32x4 acc[4][4];
    {
        short8 a[4][2];
        #pragma unroll
        for (int mt = 0; mt < 4; ++mt)
            #pragma unroll
            for (int s = 0; s < 2; ++s)
                a[mt][s] = *(const short8*)&lds[(mt * 16 + m) * YSTR + s * 32 + g * 8];
        #pragma unroll
        for (int nt4 = 0; nt4 < 4; ++nt4) {
            int nt = w * 4 + nt4;
            short8 b0  = w1f[nt * 64 + lane];
            short8 b1v = w1f[(16 + nt) * 64 + lane];
            float bias = b1[nt * 16 + m];
            #pragma unroll
            for (int mt = 0; mt < 4; ++mt) {
                f32x4 c = {bias, bias, bias, bias};
                c = __builtin_amdgcn_mfma_f32_16x16x32_bf16(a[mt][0], b0,  c, 0, 0, 0);
                c = __builtin_amdgcn_mfma_f32_16x16x32_bf16(a[mt][1], b1v, c, 0, 0, 0);
                acc[mt][nt4] = c;
            }
        }
    }
    __syncthreads();

    {
        #pragma unroll
        for (int mt = 0; mt < 4; ++mt)
            #pragma unroll
            for (int nt4 = 0; nt4 < 4; ++nt4) {
                int col = w * 64 + nt4 * 16 + m;
                #pragma unroll
                for (int r = 0; r < 4; ++r) {
                    float hv = fmaxf(acc[mt][nt4][r], 0.f);
                    lds[(mt * 16 + g * 4 + r) * HSTR + col] = (short)bf16r(hv);
                }
            }
    }
    __syncthreads();

    {
        short8 a2[8];
        #pragma unroll
        for (int s = 0; s < 8; ++s)
            a2[s] = *(const short8*)&lds[(w * 16 + m) * HSTR + s * 32 + g * 8];
        #pragma unroll
        for (int nt = 0; nt < 3; ++nt) {
            int col = nt * 16 + m;
            float bias = (col < NC) ? b2[col] : 0.f;
            f32x4 c = {bias, bias, bias, bias};
            #pragma unroll
            for (int s = 0; s < 8; ++s)
                c = __builtin_amdgcn_mfma_f32_16x16x32_bf16(a2[s], w2f[(s * 3 + nt) * 64 + lane], c, 0, 0, 0);
            if (col < NC) {
                #pragma unroll
                for (int r = 0; r < 4; ++r) {
                    int row = base + w * 16 + g * 4 + r;
                    if (row < n) out[(size_t)row * NC + col] = c[r];
                }
            }
        }
    }
}

// ---------------- launch ----------------

extern "C" void kernel_launch(void* const* d_in, const int* in_sizes, int n_in,
                              void* d_out, int out_size, void* d_ws, size_t ws_size,
                              hipStream_t stream)
{
    const float* x  = (const float*)d_in[0];
    const int*   ei = (const int*)d_in[1];
    const float* W1 = (const float*)d_in[2];
    const float* b1 = (const float*)d_in[3];
    const float* W2 = (const float*)d_in[4];
    const float* b2 = (const float*)d_in[5];
    float* out = (float*)d_out;

    const int n = NN, E = NE;
    const int nb = (n + SC - 1) / SC;  // 98 scan blocks

    char* ws = (char*)d_ws;
    size_t off = 0;
    auto alloc = [&](size_t bytes) -> void* {
        void* p = ws + off;
        off = (off + bytes + 255) & ~(size_t)255;
        return p;
    };
    int*    cnt  = (int*)   alloc((size_t)n * 4);
    int*    fill = (int*)   alloc((size_t)n * 4);
    int*    rp   = (int*)   alloc((size_t)(n + 1) * 4);
    float2* drd  = (float2*)alloc((size_t)n * 8);
    int*    bsum = (int*)   alloc(128 * 4);
    int*    boff = (int*)   alloc(128 * 4);
    int*    bcnt = (int*)   alloc(8 * 4);
    int2*   bbuf = (int2*)  alloc((size_t)8 * BCAP * 8);
    int*    ccol = (int*)   alloc((size_t)E * 4);
    unsigned short* w1f = (unsigned short*)alloc(2048 * 8 * 2);
    unsigned short* w2f = (unsigned short*)alloc(1536 * 8 * 2);
    uint4* ha   = (uint4*)alloc((size_t)n * NF * 2);   // bf16 g ping
    uint4* hbuf = (uint4*)alloc((size_t)n * NF * 2);   // bf16 g pong
    float* y    = (float*)alloc((size_t)n * NF * 4);   // f32 accumulator

    hipMemsetAsync(cnt, 0, (size_t)n * 4, stream);
    hipMemsetAsync(bcnt, 0, 8 * 4, stream);

    const int* rows = ei;
    const int* cols = ei + E;

    k_bin   <<<(E + BINB - 1) / BINB, 256, 0, stream>>>(rows, cols, cnt, bcnt, bbuf, E);
    k_bsum  <<<nb, 256, 0, stream>>>(cnt, bsum, n);
    k_scanb <<<1, 128, 0, stream>>>(bsum, boff, rp, nb, n);
    k_scan3 <<<nb, 256, 0, stream>>>(cnt, boff, rp, drd, n);
    hipMemcpyAsync(fill, rp, (size_t)n * 4, hipMemcpyDeviceToDevice, stream);
    k_scat2 <<<4096, 256, 0, stream>>>(bbuf, bcnt, fill, ccol);
    k_pack  <<<14, 256, 0, stream>>>(W1, W2, w1f, w2f);

    int nchunk = n * 8;
    k_init<<<(nchunk + 255) / 256, 256, 0, stream>>>((const float4*)x, (float4*)y,
                                                     ha, drd, nchunk);

    uint4* cur = ha;
    uint4* nxt = hbuf;
    int spmm_blocks = (n + 15) / 16;   // 4 rows/wave, 4 waves/block
    for (int it = 0; it < ORDER_C; ++it) {
        if (it & 1)
            k_spmm<true><<<spmm_blocks, 256, 0, stream>>>((const uint2*)cur, (uint2*)nxt,
                                                          (float4*)y, rp, ccol, drd, n);
        else
            k_spmm<false><<<spmm_blocks, 256, 0, stream>>>((const uint2*)cur, (uint2*)nxt,
                                                           (float4*)y, rp, ccol, drd, n);
        uint4* tswap = cur; cur = nxt; nxt = tswap;
    }

    k_mlp<<<(n + 63) / 64, 256, 0, stream>>>((const float4*)y, (const short8*)w1f,
                                             (const short8*)w2f, b1, b2, out, n);
}